// Round 1
// baseline (1428.547 us; speedup 1.0000x reference)
//
#include <hip/hip_runtime.h>
#include <math.h>

#define NEG_INF (-__builtin_inff())

// ---------------------------------------------------------------------------
// pack conv-k3 weights (O, Cin, 3) -> (3, O, Cin)
__global__ void pack_w_kernel(const float* __restrict__ src, float* __restrict__ dst,
                              int O, int Cin) {
    int idx = blockIdx.x * 256 + threadIdx.x;
    int tot = 3 * O * Cin;
    if (idx >= tot) return;
    int w = idx / (O * Cin);
    int r = idx - w * O * Cin;
    int o = r / Cin, i = r - o * Cin;
    dst[idx] = src[(o * Cin + i) * 3 + w];
}

// ---------------------------------------------------------------------------
// out[b,c,t] = keys[b,c,t] + style[b,t,c]   (style transposed via LDS tile)
__global__ void transpose_add_kernel(const float* __restrict__ keys,
                                     const float* __restrict__ style,
                                     float* __restrict__ out, int C, int T) {
    int b = blockIdx.z;
    int t0 = blockIdx.x * 32, c0 = blockIdx.y * 32;
    __shared__ float tile[32][33];
    int tx = threadIdx.x, ty = threadIdx.y;  // (32, 8)
    #pragma unroll
    for (int j = 0; j < 32; j += 8) {
        int t = t0 + ty + j, c = c0 + tx;
        tile[ty + j][tx] = (t < T && c < C) ? style[((size_t)b * T + t) * C + c] : 0.f;
    }
    __syncthreads();
    #pragma unroll
    for (int j = 0; j < 32; j += 8) {
        int c = c0 + ty + j, t = t0 + tx;
        if (c < C && t < T) {
            size_t o = ((size_t)b * C + c) * T + t;
            out[o] = keys[o] + tile[tx][ty + j];
        }
    }
}

// ---------------------------------------------------------------------------
// Generic tiled SGEMM for conv1d (KW=3 with on-the-fly im2col, or KW=1):
// Y[b,o,t] = act( bias[o] + sum_{w,i} A[w,o,i] * X[b,i,t+w-1] )
// A packed as (KW, O, Cin). BM=BN=64, BK=16, 256 threads, 4x4 per thread.
__global__ __launch_bounds__(256) void gemm_conv_kernel(
    const float* __restrict__ A, const float* __restrict__ X,
    const float* __restrict__ bias, float* __restrict__ Y,
    int O, int Cin, int T, int KW, int act) {
    const int BM = 64, BN = 64, BK = 16;
    int b = blockIdx.z;
    int m0 = blockIdx.y * BM;
    int n0 = blockIdx.x * BN;
    const float* Xb = X + (size_t)b * Cin * T;
    float* Yb = Y + (size_t)b * O * T;

    __shared__ __align__(16) float As[BK][BM + 4];
    __shared__ __align__(16) float Bs[BK][BN + 4];

    int tid = threadIdx.x;
    int am = tid >> 2;             // 0..63 (m within tile)
    int ak = (tid & 3) * 4;        // k offset 0,4,8,12
    int bk = tid >> 4;             // 0..15 (k within tile)
    int bn = (tid & 15) * 4;       // n offset
    int ty = tid >> 4, tx = tid & 15;

    float acc[4][4] = {};
    int Ktot = KW * Cin;
    for (int k0 = 0; k0 < Ktot; k0 += BK) {
        int w = k0 / Cin;           // Cin % 16 == 0 for all our shapes
        int i0 = k0 - w * Cin;
        // A tile
        {
            int m = m0 + am;
            float4 av = make_float4(0.f, 0.f, 0.f, 0.f);
            if (m < O)
                av = *reinterpret_cast<const float4*>(A + ((size_t)w * O + m) * Cin + i0 + ak);
            As[ak + 0][am] = av.x;
            As[ak + 1][am] = av.y;
            As[ak + 2][am] = av.z;
            As[ak + 3][am] = av.w;
        }
        // B tile (zero-padded shifted columns)
        {
            int i = i0 + bk;
            int shift = (KW == 3) ? (w - 1) : 0;
            const float* xp = Xb + (size_t)i * T;
            float4 bv;
            int c0 = n0 + bn + shift;
            bv.x = (c0 + 0 >= 0 && c0 + 0 < T) ? xp[c0 + 0] : 0.f;
            bv.y = (c0 + 1 >= 0 && c0 + 1 < T) ? xp[c0 + 1] : 0.f;
            bv.z = (c0 + 2 >= 0 && c0 + 2 < T) ? xp[c0 + 2] : 0.f;
            bv.w = (c0 + 3 >= 0 && c0 + 3 < T) ? xp[c0 + 3] : 0.f;
            *reinterpret_cast<float4*>(&Bs[bk][bn]) = bv;
        }
        __syncthreads();
        #pragma unroll
        for (int kk = 0; kk < BK; ++kk) {
            float a[4], bb[4];
            *reinterpret_cast<float4*>(a)  = *reinterpret_cast<const float4*>(&As[kk][ty * 4]);
            *reinterpret_cast<float4*>(bb) = *reinterpret_cast<const float4*>(&Bs[kk][tx * 4]);
            #pragma unroll
            for (int mi = 0; mi < 4; ++mi)
                #pragma unroll
                for (int ni = 0; ni < 4; ++ni)
                    acc[mi][ni] = fmaf(a[mi], bb[ni], acc[mi][ni]);
        }
        __syncthreads();
    }
    #pragma unroll
    for (int mi = 0; mi < 4; ++mi) {
        int m = m0 + ty * 4 + mi;
        if (m >= O) continue;
        float bs = bias[m];
        #pragma unroll
        for (int ni = 0; ni < 4; ++ni) {
            int n = n0 + tx * 4 + ni;
            if (n < T) {
                float v = acc[mi][ni] + bs;
                if (act) v = fmaxf(v, 0.f);
                Yb[(size_t)m * T + n] = v;
            }
        }
    }
}

// ---------------------------------------------------------------------------
// out[b,t] = sum_c X[b,c,t]^2
__global__ void sqsum_kernel(const float* __restrict__ X, float* __restrict__ out,
                             int C, int T) {
    int b = blockIdx.y;
    int t = blockIdx.x * 256 + threadIdx.x;
    if (t >= T) return;
    const float* xb = X + (size_t)b * C * T + t;
    float s = 0.f;
    for (int c = 0; c < C; ++c) {
        float v = xb[(size_t)c * T];
        s = fmaf(v, v, s);
    }
    out[(size_t)b * T + t] = s;
}

// ---------------------------------------------------------------------------
// logits[b,t,s] = SCALE*(q2[b,t] + k2[b,s] - 2*sum_c q[b,c,t]*k[b,c,s])
__global__ __launch_bounds__(256) void dist_kernel(
    const float* __restrict__ q, const float* __restrict__ k,
    const float* __restrict__ q2, const float* __restrict__ k2,
    float* __restrict__ logits, int T1, int T2, int C) {
    const float SCALE = -0.0005f;
    int b = blockIdx.z;
    int m0 = blockIdx.y * 64;  // t
    int n0 = blockIdx.x * 64;  // s
    __shared__ __align__(16) float As[16][68];
    __shared__ __align__(16) float Bs[16][68];
    const float* qb = q + (size_t)b * C * T1;
    const float* kb = k + (size_t)b * C * T2;
    int tid = threadIdx.x;
    int lk = tid >> 4, ln = (tid & 15) * 4;
    int ty = tid >> 4, tx = tid & 15;
    float acc[4][4] = {};
    for (int c0 = 0; c0 < C; c0 += 16) {
        {
            const float* p = qb + (size_t)(c0 + lk) * T1 + m0 + ln;
            #pragma unroll
            for (int j = 0; j < 4; ++j)
                As[lk][ln + j] = (m0 + ln + j < T1) ? p[j] : 0.f;
        }
        {
            const float* p = kb + (size_t)(c0 + lk) * T2 + n0 + ln;
            #pragma unroll
            for (int j = 0; j < 4; ++j)
                Bs[lk][ln + j] = (n0 + ln + j < T2) ? p[j] : 0.f;
        }
        __syncthreads();
        #pragma unroll
        for (int kk = 0; kk < 16; ++kk) {
            float a[4], bb[4];
            *reinterpret_cast<float4*>(a)  = *reinterpret_cast<const float4*>(&As[kk][ty * 4]);
            *reinterpret_cast<float4*>(bb) = *reinterpret_cast<const float4*>(&Bs[kk][tx * 4]);
            #pragma unroll
            for (int mi = 0; mi < 4; ++mi)
                #pragma unroll
                for (int ni = 0; ni < 4; ++ni)
                    acc[mi][ni] = fmaf(a[mi], bb[ni], acc[mi][ni]);
        }
        __syncthreads();
    }
    #pragma unroll
    for (int mi = 0; mi < 4; ++mi) {
        int t = m0 + ty * 4 + mi;
        if (t >= T1) continue;
        float qq = q2[(size_t)b * T1 + t];
        #pragma unroll
        for (int ni = 0; ni < 4; ++ni) {
            int s = n0 + tx * 4 + ni;
            if (s < T2)
                logits[((size_t)b * T1 + t) * T2 + s] =
                    SCALE * (qq + k2[(size_t)b * T2 + s] - 2.f * acc[mi][ni]);
        }
    }
}

// ---------------------------------------------------------------------------
// Per row (b,t): log_softmax over s + log(prior+eps) -> logp (in place);
// masked softmax -> attn. One wave per row, T2=400 -> 7 elems/lane.
__global__ __launch_bounds__(256) void softmax_kernel(
    float* __restrict__ logp, float* __restrict__ attn,
    const float* __restrict__ prior, const unsigned char* __restrict__ mask,
    int T1) {
    const int T2 = 400;
    int wid = threadIdx.x >> 6, lane = threadIdx.x & 63;
    int row = blockIdx.x * 4 + wid;
    int b = row / T1;
    size_t base = (size_t)row * T2;

    float v[7];
    #pragma unroll
    for (int j = 0; j < 7; ++j) {
        int s = lane + j * 64;
        v[j] = (s < T2) ? logp[base + s] : NEG_INF;
    }
    float mx = NEG_INF;
    #pragma unroll
    for (int j = 0; j < 7; ++j) mx = fmaxf(mx, v[j]);
    #pragma unroll
    for (int off = 32; off; off >>= 1) mx = fmaxf(mx, __shfl_xor(mx, off));
    float sum = 0.f;
    #pragma unroll
    for (int j = 0; j < 7; ++j) {
        int s = lane + j * 64;
        if (s < T2) sum += __expf(v[j] - mx);
    }
    #pragma unroll
    for (int off = 32; off; off >>= 1) sum += __shfl_xor(sum, off);
    float lse = mx + __logf(sum);

    float mv[7];
    float mx2 = NEG_INF;
    #pragma unroll
    for (int j = 0; j < 7; ++j) {
        int s = lane + j * 64;
        if (s < T2) {
            float lp = v[j] - lse + __logf(prior[base + s] + 1e-8f);
            logp[base + s] = lp;
            bool m = mask[(size_t)b * T2 + s] != 0;
            mv[j] = m ? NEG_INF : lp;
            mx2 = fmaxf(mx2, mv[j]);
        } else {
            mv[j] = NEG_INF;
        }
    }
    #pragma unroll
    for (int off = 32; off; off >>= 1) mx2 = fmaxf(mx2, __shfl_xor(mx2, off));
    float s2 = 0.f;
    #pragma unroll
    for (int j = 0; j < 7; ++j) {
        int s = lane + j * 64;
        if (s < T2 && mv[j] > NEG_INF) s2 += __expf(mv[j] - mx2);
    }
    #pragma unroll
    for (int off = 32; off; off >>= 1) s2 += __shfl_xor(s2, off);
    float inv = 1.f / s2;
    #pragma unroll
    for (int j = 0; j < 7; ++j) {
        int s = lane + j * 64;
        if (s < T2)
            attn[base + s] = (mv[j] > NEG_INF) ? __expf(mv[j] - mx2) * inv : 0.f;
    }
}

// ---------------------------------------------------------------------------
extern "C" void kernel_launch(void* const* d_in, const int* in_sizes, int n_in,
                              void* d_out, int out_size, void* d_ws, size_t ws_size,
                              hipStream_t stream) {
    const float* queries = (const float*)d_in[0];   // (32,80,2000)
    const float* keys    = (const float*)d_in[1];   // (32,512,400)
    const unsigned char* mask = (const unsigned char*)d_in[3];  // (32,400,1) bool
    const float* prior   = (const float*)d_in[4];   // (32,2000,400)
    const float* style   = (const float*)d_in[5];   // (32,400,512)
    const float* qw1 = (const float*)d_in[6];
    const float* qb1 = (const float*)d_in[7];
    const float* qw2 = (const float*)d_in[8];
    const float* qb2 = (const float*)d_in[9];
    const float* qw3 = (const float*)d_in[10];
    const float* qb3 = (const float*)d_in[11];
    const float* kw1 = (const float*)d_in[12];
    const float* kb1 = (const float*)d_in[13];
    const float* kw2 = (const float*)d_in[14];
    const float* kb2 = (const float*)d_in[15];

    const int B = 32, T1 = 2000, T2 = 400;

    float* ws   = (float*)d_ws;
    float* WpkK = ws;                              // 3*1024*512 = 1,572,864
    float* WpkQ = WpkK + 3 * 1024 * 512;           // 3*160*80   = 38,400
    float* bufA = WpkQ + 3 * 160 * 80;             // khid (13,107,200) / qhid1 (10,240,000)
    float* bufB = bufA + (size_t)32 * 1024 * 400;  // k_pre (6,553,600) / qhid2 (5,120,000)
    float* kf   = bufB + (size_t)32 * 512 * 400;   // 1,024,000
    float* qf   = kf + (size_t)32 * 80 * 400;      // 5,120,000
    float* q2   = qf + (size_t)32 * 80 * 2000;     // 64,000
    float* k2   = q2 + (size_t)32 * 2000;          // 12,800

    float* attn = (float*)d_out;
    float* logp = attn + (size_t)B * T1 * T2;

    // 1. pack k3 weights
    pack_w_kernel<<<(3 * 1024 * 512 + 255) / 256, 256, 0, stream>>>(kw1, WpkK, 1024, 512);
    pack_w_kernel<<<(3 * 160 * 80 + 255) / 256, 256, 0, stream>>>(qw1, WpkQ, 160, 80);
    // 2. k_pre = keys + style^T
    transpose_add_kernel<<<dim3(13, 16, B), dim3(32, 8), 0, stream>>>(keys, style, bufB, 512, 400);
    // 3. K conv k3 + relu  (1024 x 400, K=1536)
    gemm_conv_kernel<<<dim3(7, 16, B), 256, 0, stream>>>(WpkK, bufB, kb1, bufA, 1024, 512, 400, 3, 1);
    // 4. K 1x1             (80 x 400, K=1024)
    gemm_conv_kernel<<<dim3(7, 2, B), 256, 0, stream>>>(kw2, bufA, kb2, kf, 80, 1024, 400, 1, 0);
    // 5. k2 sums
    sqsum_kernel<<<dim3(2, B), 256, 0, stream>>>(kf, k2, 80, 400);
    // 6. Q conv k3 + relu  (160 x 2000, K=240)
    gemm_conv_kernel<<<dim3(32, 3, B), 256, 0, stream>>>(WpkQ, queries, qb1, bufA, 160, 80, 2000, 3, 1);
    // 7. Q 1x1 + relu      (80 x 2000, K=160)
    gemm_conv_kernel<<<dim3(32, 2, B), 256, 0, stream>>>(qw2, bufA, qb2, bufB, 80, 160, 2000, 1, 1);
    // 8. Q 1x1             (80 x 2000, K=80)
    gemm_conv_kernel<<<dim3(32, 2, B), 256, 0, stream>>>(qw3, bufB, qb3, qf, 80, 80, 2000, 1, 0);
    // 9. q2 sums
    sqsum_kernel<<<dim3(8, B), 256, 0, stream>>>(qf, q2, 80, 2000);
    // 10. distance -> raw logits (stored where attn_logprob goes)
    dist_kernel<<<dim3(7, 32, B), 256, 0, stream>>>(qf, kf, q2, k2, logp, T1, T2, 80);
    // 11. fused double softmax
    softmax_kernel<<<16000, 256, 0, stream>>>(logp, attn, prior, mask, T1);
}

// Round 6
// 602.299 us; speedup vs baseline: 2.3718x; 2.3718x over previous
//
#include <hip/hip_runtime.h>
#include <math.h>

#define NEG_INF (-__builtin_inff())

typedef short short8 __attribute__((ext_vector_type(8)));
typedef float f32x4 __attribute__((ext_vector_type(4)));
typedef unsigned short ushort4v __attribute__((ext_vector_type(4)));

__device__ __forceinline__ unsigned short f2bf(float f) {
    unsigned int u = __float_as_uint(f);
    u += 0x7fffu + ((u >> 16) & 1u);
    return (unsigned short)(u >> 16);
}
__device__ __forceinline__ float bf2f(unsigned short s) {
    return __uint_as_float(((unsigned int)s) << 16);
}

// ---------------------------------------------------------------------------
// Weights: src (O, Cin, KW) -> dst[w][o][i] over [KW][Mpad][Kpad], zero-padded.
__global__ void convert_w_kernel(const float* __restrict__ src, unsigned short* __restrict__ dst,
                                 int KW, int O, int Cin, int Mpad, int Kpad) {
    int idx = blockIdx.x * 256 + threadIdx.x;
    int tot = KW * Mpad * Kpad;
    if (idx >= tot) return;
    int w = idx / (Mpad * Kpad);
    int r = idx - w * Mpad * Kpad;
    int o = r / Kpad, i = r - o * Kpad;
    float v = (o < O && i < Cin) ? src[((size_t)o * Cin + i) * KW + w] : 0.f;
    dst[idx] = f2bf(v);
}

// ---------------------------------------------------------------------------
// out[b][tt][c] (bf16, Rows x ldC) = in[b][c][tt-1] (+ style[b][tt-1][c]) , 0 outside.
__global__ void transpose_in_kernel(const float* __restrict__ in,
                                    const float* __restrict__ style,
                                    unsigned short* __restrict__ out,
                                    int C, int T, int Rows, int ldC) {
    int b = blockIdx.z;
    int tt0 = blockIdx.x * 32, c0 = blockIdx.y * 32;
    int tx = threadIdx.x, ty = threadIdx.y;   // (32,8)
    __shared__ float tile[32][33];
    const float* inb = in + (size_t)b * C * T;
    int t_load = tt0 - 1 + tx;
    #pragma unroll
    for (int j = 0; j < 32; j += 8) {
        int c = c0 + ty + j;
        tile[ty + j][tx] = (t_load >= 0 && t_load < T && c < C)
                               ? inb[(size_t)c * T + t_load] : 0.f;
    }
    __syncthreads();
    #pragma unroll
    for (int j = 0; j < 32; j += 8) {
        int tt = tt0 + ty + j;
        int c = c0 + tx;
        if (tt >= Rows) continue;
        int t = tt - 1;
        float v = 0.f;
        if (t >= 0 && t < T && c < C) {
            v = tile[tx][ty + j];
            if (style) v += style[((size_t)b * T + t) * C + c];
        }
        out[((size_t)b * Rows + tt) * ldC + c] = f2bf(v);
    }
}

// ---------------------------------------------------------------------------
// k2[b*448+s] = sum_c kf_T[b][s][c]^2   (128 cols)
__global__ void k2_kernel(const unsigned short* __restrict__ kf, float* __restrict__ k2) {
    int idx = blockIdx.x * 256 + threadIdx.x;
    if (idx >= 32 * 448) return;
    const unsigned short* p = kf + (size_t)idx * 128;
    float s = 0.f;
    #pragma unroll 8
    for (int i = 0; i < 128; ++i) { float v = bf2f(p[i]); s = fmaf(v, v, s); }
    k2[idx] = s;
}

// ---------------------------------------------------------------------------
// bf16 MFMA GEMM, block tile 128(M) x 64(N), BK=64, 4 waves (2x2), wave 64x32.
// A: [KW][MpadA][Cpad] bf16 (k-contiguous rows), batch stride sA (0 = shared).
// B: rows [.][Cpad] bf16 per batch (stride sB); row index for output col t is (t + w).
// MODE 0: out bf16 [n][ldY] transposed, bias+optional relu, zeros for n>=Nvalid or m>=O.
// MODE 1: dist: out fp32 logits[m*ldY+n] = SCALE*(k2[n] - 2*acc), m<O(=2000), n<Nvalid(=400).
template <int MODE>
__global__ __launch_bounds__(256) void mfma_gemm_kernel(
    const unsigned short* __restrict__ A, const unsigned short* __restrict__ Bmat,
    const float* __restrict__ bias, void* __restrict__ outp,
    const float* __restrict__ k2,
    int Cpad, int KW, int MpadA, size_t sA, size_t sB,
    int O, int Opadw, int Nvalid, int ldY, size_t sY, int relu) {
    const int tid = threadIdx.x;
    const int b = blockIdx.z;
    const int m0 = blockIdx.y * 128;
    const int t0 = blockIdx.x * 64;
    const unsigned short* Ab = A + (size_t)b * sA;
    const unsigned short* Bb = Bmat + (size_t)b * sB;

    __shared__ __align__(16) char As[128 * 128];   // 128 rows x 128 B (BK=64 bf16)
    __shared__ __align__(16) char Bs[64 * 128];

    const int lane = tid & 63, wid = tid >> 6;
    const int wm0 = (wid >> 1) * 64, wn0 = (wid & 1) * 32;
    const int fr = lane & 15;         // fragment row (m for A, n for B)
    const int kb = (lane >> 4) * 16;  // byte offset of lane's 8 bf16 in 64B half

    f32x4 acc[4][2] = {};

    const int sr = tid >> 3;          // 0..31
    const int sc = (tid & 7) * 16;    // byte col in 128B row

    for (int w = 0; w < KW; ++w) {
        const unsigned short* Aw = Ab + (size_t)w * MpadA * Cpad;
        for (int i0 = 0; i0 < Cpad; i0 += 64) {
            #pragma unroll
            for (int rep = 0; rep < 4; ++rep) {       // A: 128 rows
                int r = rep * 32 + sr;
                const char* src = (const char*)(Aw + (size_t)(m0 + r) * Cpad + i0) + sc;
                short8 v = *(const short8*)src;
                *(short8*)(As + r * 128 + (sc ^ ((r & 7) << 4))) = v;
            }
            #pragma unroll
            for (int rep = 0; rep < 2; ++rep) {       // B: 64 rows at t0+w
                int r = rep * 32 + sr;
                const char* src = (const char*)(Bb + (size_t)(t0 + w + r) * Cpad + i0) + sc;
                short8 v = *(const short8*)src;
                *(short8*)(Bs + r * 128 + (sc ^ ((r & 7) << 4))) = v;
            }
            __syncthreads();
            #pragma unroll
            for (int hk = 0; hk < 2; ++hk) {
                short8 af[4], bfr[2];
                #pragma unroll
                for (int fm = 0; fm < 4; ++fm) {
                    int row = wm0 + fm * 16 + fr;
                    int col = (hk * 64 + kb) ^ ((row & 7) << 4);
                    af[fm] = *(const short8*)(As + row * 128 + col);
                }
                #pragma unroll
                for (int fn = 0; fn < 2; ++fn) {
                    int row = wn0 + fn * 16 + fr;
                    int col = (hk * 64 + kb) ^ ((row & 7) << 4);
                    bfr[fn] = *(const short8*)(Bs + row * 128 + col);
                }
                #pragma unroll
                for (int fm = 0; fm < 4; ++fm)
                    #pragma unroll
                    for (int fn = 0; fn < 2; ++fn)
                        acc[fm][fn] = __builtin_amdgcn_mfma_f32_16x16x32_bf16(
                            af[fm], bfr[fn], acc[fm][fn], 0, 0, 0);
            }
            __syncthreads();
        }
    }

    if (MODE == 0) {
        unsigned short* Y = (unsigned short*)outp + (size_t)b * sY;
        #pragma unroll
        for (int fm = 0; fm < 4; ++fm) {
            int mb = m0 + wm0 + fm * 16 + (lane >> 4) * 4;
            if (mb >= Opadw) continue;
            #pragma unroll
            for (int fn = 0; fn < 2; ++fn) {
                int n = t0 + wn0 + fn * 16 + fr;
                bool nval = n < Nvalid;
                ushort4v pk;
                #pragma unroll
                for (int j = 0; j < 4; ++j) {
                    int m = mb + j;
                    float v = 0.f;
                    if (nval && m < O) {
                        v = acc[fm][fn][j] + bias[m];
                        if (relu) v = fmaxf(v, 0.f);
                    }
                    pk[j] = f2bf(v);
                }
                *(ushort4v*)(Y + (size_t)n * ldY + mb) = pk;
            }
        }
    } else {
        float* logits = (float*)outp + (size_t)b * sY;
        const float* k2b = k2 + (size_t)b * 448;
        #pragma unroll
        for (int fm = 0; fm < 4; ++fm) {
            int mb = m0 + wm0 + fm * 16 + (lane >> 4) * 4;
            #pragma unroll
            for (int fn = 0; fn < 2; ++fn) {
                int n = t0 + wn0 + fn * 16 + fr;
                if (n >= Nvalid) continue;
                float kk = k2b[n];
                #pragma unroll
                for (int j = 0; j < 4; ++j) {
                    int m = mb + j;
                    if (m < O)
                        logits[(size_t)m * ldY + n] = -0.0005f * (kk - 2.f * acc[fm][fn][j]);
                }
            }
        }
    }
}

// ---------------------------------------------------------------------------
// Per row (b,t): log_softmax over s + log(prior+eps) -> logp (in place);
// masked softmax -> attn. One wave per row, T2=400 -> 7 elems/lane.
__global__ __launch_bounds__(256) void softmax_kernel(
    float* __restrict__ logp, float* __restrict__ attn,
    const float* __restrict__ prior, const unsigned char* __restrict__ mask,
    int T1) {
    const int T2 = 400;
    int wid = threadIdx.x >> 6, lane = threadIdx.x & 63;
    int row = blockIdx.x * 4 + wid;
    int b = row / T1;
    size_t base = (size_t)row * T2;

    float v[7];
    #pragma unroll
    for (int j = 0; j < 7; ++j) {
        int s = lane + j * 64;
        v[j] = (s < T2) ? logp[base + s] : NEG_INF;
    }
    float mx = NEG_INF;
    #pragma unroll
    for (int j = 0; j < 7; ++j) mx = fmaxf(mx, v[j]);
    #pragma unroll
    for (int off = 32; off; off >>= 1) mx = fmaxf(mx, __shfl_xor(mx, off));
    float sum = 0.f;
    #pragma unroll
    for (int j = 0; j < 7; ++j) {
        int s = lane + j * 64;
        if (s < T2) sum += __expf(v[j] - mx);
    }
    #pragma unroll
    for (int off = 32; off; off >>= 1) sum += __shfl_xor(sum, off);
    float lse = mx + __logf(sum);

    float mv[7];
    float mx2 = NEG_INF;
    #pragma unroll
    for (int j = 0; j < 7; ++j) {
        int s = lane + j * 64;
        if (s < T2) {
            float lp = v[j] - lse + __logf(prior[base + s] + 1e-8f);
            logp[base + s] = lp;
            bool m = mask[(size_t)b * T2 + s] != 0;
            mv[j] = m ? NEG_INF : lp;
            mx2 = fmaxf(mx2, mv[j]);
        } else {
            mv[j] = NEG_INF;
        }
    }
    #pragma unroll
    for (int off = 32; off; off >>= 1) mx2 = fmaxf(mx2, __shfl_xor(mx2, off));
    float s2 = 0.f;
    #pragma unroll
    for (int j = 0; j < 7; ++j) {
        int s = lane + j * 64;
        if (s < T2 && mv[j] > NEG_INF) s2 += __expf(mv[j] - mx2);
    }
    #pragma unroll
    for (int off = 32; off; off >>= 1) s2 += __shfl_xor(s2, off);
    float inv = 1.f / s2;
    #pragma unroll
    for (int j = 0; j < 7; ++j) {
        int s = lane + j * 64;
        if (s < T2)
            attn[base + s] = (mv[j] > NEG_INF) ? __expf(mv[j] - mx2) * inv : 0.f;
    }
}

// ---------------------------------------------------------------------------
extern "C" void kernel_launch(void* const* d_in, const int* in_sizes, int n_in,
                              void* d_out, int out_size, void* d_ws, size_t ws_size,
                              hipStream_t stream) {
    const float* queries = (const float*)d_in[0];   // (32,80,2000)
    const float* keys    = (const float*)d_in[1];   // (32,512,400)
    const unsigned char* mask = (const unsigned char*)d_in[3];  // (32,400,1)
    const float* prior   = (const float*)d_in[4];   // (32,2000,400)
    const float* style   = (const float*)d_in[5];   // (32,400,512)
    const float* qw1 = (const float*)d_in[6];
    const float* qb1 = (const float*)d_in[7];
    const float* qw2 = (const float*)d_in[8];
    const float* qb2 = (const float*)d_in[9];
    const float* qw3 = (const float*)d_in[10];
    const float* qb3 = (const float*)d_in[11];
    const float* kw1 = (const float*)d_in[12];
    const float* kb1 = (const float*)d_in[13];
    const float* kw2 = (const float*)d_in[14];
    const float* kb2 = (const float*)d_in[15];

    const int B = 32, T1 = 2000, T2 = 400;

    // workspace layout (bf16 elems)
    unsigned short* ws = (unsigned short*)d_ws;
    unsigned short* WpkK  = ws;                      // [3][1024][512]   1572864
    unsigned short* Wk2   = ws + 1572864;            // [128][1024]      131072
    unsigned short* WpkQ1 = ws + 1703936;            // [3][256][128]    98304
    unsigned short* Wq2   = ws + 1802240;            // [128][192]       24576
    unsigned short* Wq3   = ws + 1826816;            // [128][128]       16384
    unsigned short* kpreT = ws + 1843200;            // 32*[452][512]    7405568
    unsigned short* khidT = ws + 9248768;            // 32*[448][1024]   14680064
    unsigned short* qh1T  = khidT;                   // alias: 32*[2048][192] 12582912
    unsigned short* qinT  = ws + 23928832;           // 32*[2052][128]   8404992
    unsigned short* qh2T  = qinT;                    // alias: 32*[2048][128] 8388608
    unsigned short* kfT   = ws + 32333824;           // 32*[448][128]    1835008
    unsigned short* qfT   = ws + 34168832;           // 32*[2048][128]   8388608
    float* k2buf = (float*)((char*)d_ws + 85114880); // 32*448 fp32

    float* attn = (float*)d_out;
    float* logp = attn + (size_t)B * T1 * T2;

    // 1. weight convert/pack (zero-padded)
    convert_w_kernel<<<(3*1024*512 + 255)/256, 256, 0, stream>>>(kw1, WpkK, 3, 1024, 512, 1024, 512);
    convert_w_kernel<<<(128*1024 + 255)/256, 256, 0, stream>>>(kw2, Wk2, 1, 80, 1024, 128, 1024);
    convert_w_kernel<<<(3*256*128 + 255)/256, 256, 0, stream>>>(qw1, WpkQ1, 3, 160, 80, 256, 128);
    convert_w_kernel<<<(128*192 + 255)/256, 256, 0, stream>>>(qw2, Wq2, 1, 80, 160, 128, 192);
    convert_w_kernel<<<(128*128 + 255)/256, 256, 0, stream>>>(qw3, Wq3, 1, 80, 80, 128, 128);

    // 2. transposed, padded bf16 inputs
    transpose_in_kernel<<<dim3(15, 16, B), dim3(32, 8), 0, stream>>>(keys, style, kpreT, 512, T2, 452, 512);
    transpose_in_kernel<<<dim3(65, 4, B), dim3(32, 8), 0, stream>>>(queries, nullptr, qinT, 80, T1, 2052, 128);

    // 3. K path
    mfma_gemm_kernel<0><<<dim3(7, 8, B), 256, 0, stream>>>(
        WpkK, kpreT, kb1, khidT, nullptr, 512, 3, 1024, 0, (size_t)452*512,
        1024, 1024, 400, 1024, (size_t)448*1024, 1);
    mfma_gemm_kernel<0><<<dim3(7, 1, B), 256, 0, stream>>>(
        Wk2, khidT, kb2, kfT, nullptr, 1024, 1, 128, 0, (size_t)448*1024,
        80, 128, 400, 128, (size_t)448*128, 0);
    k2_kernel<<<(32*448 + 255)/256, 256, 0, stream>>>(kfT, k2buf);

    // 4. Q path (qh1T aliases khidT — K path is done with it; qh2T aliases qinT)
    mfma_gemm_kernel<0><<<dim3(32, 2, B), 256, 0, stream>>>(
        WpkQ1, qinT, qb1, qh1T, nullptr, 128, 3, 256, 0, (size_t)2052*128,
        160, 192, 2000, 192, (size_t)2048*192, 1);
    mfma_gemm_kernel<0><<<dim3(32, 1, B), 256, 0, stream>>>(
        Wq2, qh1T, qb2, qh2T, nullptr, 192, 1, 128, 0, (size_t)2048*192,
        80, 128, 2000, 128, (size_t)2048*128, 1);
    mfma_gemm_kernel<0><<<dim3(32, 1, B), 256, 0, stream>>>(
        Wq3, qh2T, qb3, qfT, nullptr, 128, 1, 128, 0, (size_t)2048*128,
        80, 128, 2000, 128, (size_t)2048*128, 0);

    // 5. distance logits -> logp region (q2 term dropped: row-constant, softmax-invariant)
    mfma_gemm_kernel<1><<<dim3(7, 16, B), 256, 0, stream>>>(
        qfT, kfT, nullptr, logp, k2buf, 128, 1, 2048, (size_t)2048*128, (size_t)448*128,
        2000, 0, 400, 400, (size_t)800000, 0);

    // 6. fused double softmax
    softmax_kernel<<<16000, 256, 0, stream>>>(logp, attn, prior, mask, T1);
}